// Round 2
// baseline (134.446 us; speedup 1.0000x reference)
//
#include <hip/hip_runtime.h>
#include <hip/hip_bf16.h>

// out[b,i,j] = sum_h a[h] * tanh(ca[b,i,h] + da[b,j,h] + bias[h])
//   via tanh(x) = 1 - 2/(e^{2x}+1),  e^{2x} = pu*pv
//   pu[b,i,h] = exp2(C2*(cell@w_k + bias)),  pv[b,h,j] = exp2(C2*(drug@w_q))
//   out = (sum_h a_h) + sum_h (-2 a_h) * rcp(1 + pu_h*pv_h)
// Inner loop per h: fma + v_rcp_f32 + fma. Output is FLOAT32 (reference dtype).

#define BB    8
#define NC    1024
#define ND    1024
#define DD    64
#define HH    32
#define CHUNK 16
#define C2    2.885390081777927f   // 2*log2(e)

__global__ __launch_bounds__(256) void proj_cell_kernel(
    const float* __restrict__ cell, const float* __restrict__ w_k,
    const float* __restrict__ bias, float* __restrict__ pu)
{
    int tid = threadIdx.x;
    int h = tid & 31;
    int i = blockIdx.x * 8 + (tid >> 5);
    int b = blockIdx.y;
    const float* crow = cell + ((size_t)(b * NC + i)) * DD;
    float s = bias[h];
    #pragma unroll
    for (int d = 0; d < DD; ++d)
        s = fmaf(crow[d], w_k[d * HH + h], s);
    pu[((size_t)(b * NC + i)) * HH + h] = exp2f(C2 * s);
}

// pv layout: [B][H][ND] so the main kernel's pv loads are j-coalesced.
__global__ __launch_bounds__(256) void proj_drug_kernel(
    const float* __restrict__ drug, const float* __restrict__ w_q,
    float* __restrict__ pv)
{
    __shared__ float sd[64][65];   // +1 pad: row-stride 65 breaks the 32-bank alias
    int tid = threadIdx.x;
    int b = blockIdx.y;
    int j0 = blockIdx.x * 64;
    const float* dbase = drug + ((size_t)(b * ND + j0)) * DD;
    #pragma unroll
    for (int k = 0; k < 16; ++k) {
        int idx = k * 256 + tid;           // coalesced global read
        sd[idx >> 6][idx & 63] = dbase[idx];
    }
    __syncthreads();
    int jl = tid & 63;       // lane = j  -> coalesced pv writes
    int hg = tid >> 6;       // 0..3, wave-uniform h
    #pragma unroll
    for (int hh = 0; hh < 8; ++hh) {
        int h = hg * 8 + hh;
        float s = 0.f;
        #pragma unroll
        for (int d = 0; d < DD; ++d)
            s = fmaf(sd[jl][d], w_q[d * HH + h], s);
        pv[((size_t)(b * HH + h)) * ND + j0 + jl] = exp2f(C2 * s);
    }
}

__global__ __launch_bounds__(256) void coattn_kernel(
    const float* __restrict__ pu, const float* __restrict__ pv,
    const float* __restrict__ a, float* __restrict__ out)
{
    int tid = threadIdx.x;
    int j  = blockIdx.x * 256 + tid;   // lane = j: coalesced pv loads + out stores
    int b  = blockIdx.z;
    int i0 = blockIdx.y * CHUNK;

    float pvr[HH];
    #pragma unroll
    for (int h = 0; h < HH; ++h)
        pvr[h] = pv[((size_t)(b * HH + h)) * ND + j];

    float m2a[HH];
    float A = 0.f;
    #pragma unroll
    for (int h = 0; h < HH; ++h) {
        float av = a[h];
        m2a[h] = -2.f * av;
        A += av;
    }

    const float* purow = pu + ((size_t)(b * NC + i0)) * HH;
    float* orow = out + ((size_t)(b * NC + i0)) * ND + j;

    for (int ii = 0; ii < CHUNK; ++ii) {
        float pur[HH];
        #pragma unroll
        for (int h4 = 0; h4 < HH / 4; ++h4) {
            float4 v = reinterpret_cast<const float4*>(purow)[h4];  // wave-uniform -> broadcast
            pur[4 * h4 + 0] = v.x;
            pur[4 * h4 + 1] = v.y;
            pur[4 * h4 + 2] = v.z;
            pur[4 * h4 + 3] = v.w;
        }
        float acc = A;
        #pragma unroll
        for (int h = 0; h < HH; ++h) {
            float q = fmaf(pur[h], pvr[h], 1.0f);     // 1 + e^{2x}  (q >= 1, rcp-safe)
            float r = __builtin_amdgcn_rcpf(q);       // v_rcp_f32
            acc = fmaf(m2a[h], r, acc);               // acc += -2 a_h * r
        }
        *orow = acc;
        purow += HH;
        orow  += ND;
    }
}

extern "C" void kernel_launch(void* const* d_in, const int* in_sizes, int n_in,
                              void* d_out, int out_size, void* d_ws, size_t ws_size,
                              hipStream_t stream) {
    const float* cell = (const float*)d_in[0];
    const float* drug = (const float*)d_in[1];
    const float* w_q  = (const float*)d_in[2];
    const float* w_k  = (const float*)d_in[3];
    const float* bias = (const float*)d_in[4];
    const float* a    = (const float*)d_in[5];
    float* out = (float*)d_out;

    float* pu = (float*)d_ws;                      // [B][NC][H]  = 1 MB
    float* pv = pu + (size_t)BB * NC * HH;         // [B][H][ND]  = 1 MB

    proj_cell_kernel<<<dim3(NC / 8, BB), 256, 0, stream>>>(cell, w_k, bias, pu);
    proj_drug_kernel<<<dim3(ND / 64, BB), 256, 0, stream>>>(drug, w_q, pv);
    coattn_kernel<<<dim3(ND / 256, NC / CHUNK, BB), 256, 0, stream>>>(pu, pv, a, out);
}

// Round 3
// 126.719 us; speedup vs baseline: 1.0610x; 1.0610x over previous
//
#include <hip/hip_runtime.h>
#include <hip/hip_bf16.h>

// out[b,i,j] = sum_h a[h] * tanh(ca[b,i,h] + da[b,j,h] + bias[h])
//   tanh(x) = 1 - 2/(e^{2x}+1);  e^{2x} = pu*pv (pu,pv precomputed via exp2)
//   Pairwise common-denominator: for h-pair (0,1) with m_h = -2 a_h,
//     m0/u + m1/v = (m0*v + m1*u) * rcp(u*v),  u=1+pu0*pv0, v=1+pu1*pv1
//   -> 6 VALU + 1 v_rcp_f32 per 2 h  (halves transcendental pressure).
// Output FLOAT32 (reference dtype).

#define BB    8
#define NC    1024
#define ND    1024
#define DD    64
#define HH    32
#define CHUNK 8
#define C2    2.885390081777927f   // 2*log2(e)

__global__ __launch_bounds__(256) void proj_cell_kernel(
    const float* __restrict__ cell, const float* __restrict__ w_k,
    const float* __restrict__ bias, float* __restrict__ pu)
{
    int tid = threadIdx.x;
    int h = tid & 31;
    int i = blockIdx.x * 8 + (tid >> 5);
    int b = blockIdx.y;
    const float* crow = cell + ((size_t)(b * NC + i)) * DD;
    float s = bias[h];
    #pragma unroll
    for (int d = 0; d < DD; ++d)
        s = fmaf(crow[d], w_k[d * HH + h], s);
    pu[((size_t)(b * NC + i)) * HH + h] = exp2f(C2 * s);
}

// pv layout: [B][H][ND] so the main kernel's pv loads are j-coalesced.
__global__ __launch_bounds__(256) void proj_drug_kernel(
    const float* __restrict__ drug, const float* __restrict__ w_q,
    float* __restrict__ pv)
{
    __shared__ float sd[64][65];   // +1 pad breaks the 32-bank alias
    int tid = threadIdx.x;
    int b = blockIdx.y;
    int j0 = blockIdx.x * 64;
    const float* dbase = drug + ((size_t)(b * ND + j0)) * DD;
    #pragma unroll
    for (int k = 0; k < 16; ++k) {
        int idx = k * 256 + tid;           // coalesced global read
        sd[idx >> 6][idx & 63] = dbase[idx];
    }
    __syncthreads();
    int jl = tid & 63;       // lane = j  -> coalesced pv writes
    int hg = tid >> 6;       // 0..3, wave-uniform h
    #pragma unroll
    for (int hh = 0; hh < 8; ++hh) {
        int h = hg * 8 + hh;
        float s = 0.f;
        #pragma unroll
        for (int d = 0; d < DD; ++d)
            s = fmaf(sd[jl][d], w_q[d * HH + h], s);
        pv[((size_t)(b * HH + h)) * ND + j0 + jl] = exp2f(C2 * s);
    }
}

__global__ __launch_bounds__(256) void coattn_kernel(
    const float* __restrict__ pu, const float* __restrict__ pv,
    const float* __restrict__ a, float* __restrict__ out)
{
    int tid = threadIdx.x;
    int j  = blockIdx.x * 256 + tid;   // lane = j: coalesced pv loads + out stores
    int b  = blockIdx.z;
    int i0 = blockIdx.y * CHUNK;

    float pvr[HH];
    #pragma unroll
    for (int h = 0; h < HH; ++h)
        pvr[h] = pv[((size_t)(b * HH + h)) * ND + j];

    // a[] is loaded at uniform addresses -> scalar regs; m2a stays in SGPRs.
    float m2a[HH];
    float A = 0.f;
    #pragma unroll
    for (int h = 0; h < HH; ++h) {
        float av = a[h];
        m2a[h] = -2.f * av;
        A += av;
    }

    const float* purow = pu + ((size_t)(b * NC + i0)) * HH;
    float* orow = out + ((size_t)(b * NC + i0)) * ND + j;

    #pragma unroll
    for (int ii = 0; ii < CHUNK; ++ii) {
        float pur[HH];
        #pragma unroll
        for (int h4 = 0; h4 < HH / 4; ++h4) {
            float4 v = reinterpret_cast<const float4*>(purow + ii * HH)[h4]; // uniform -> s_load
            pur[4 * h4 + 0] = v.x;
            pur[4 * h4 + 1] = v.y;
            pur[4 * h4 + 2] = v.z;
            pur[4 * h4 + 3] = v.w;
        }
        float acc0 = A, acc1 = 0.f;   // two chains for ILP
        #pragma unroll
        for (int t = 0; t < HH / 2; ++t) {
            float u   = fmaf(pur[2 * t],     pvr[2 * t],     1.0f);
            float v   = fmaf(pur[2 * t + 1], pvr[2 * t + 1], 1.0f);
            float den = u * v;                              // <= ~1e19, fp32-safe
            float num = fmaf(m2a[2 * t + 1], u, m2a[2 * t] * v);
            float r   = __builtin_amdgcn_rcpf(den);         // one v_rcp per 2 h
            if (t & 1) acc1 = fmaf(num, r, acc1);
            else       acc0 = fmaf(num, r, acc0);
        }
        orow[ii * ND] = acc0 + acc1;
    }
}

extern "C" void kernel_launch(void* const* d_in, const int* in_sizes, int n_in,
                              void* d_out, int out_size, void* d_ws, size_t ws_size,
                              hipStream_t stream) {
    const float* cell = (const float*)d_in[0];
    const float* drug = (const float*)d_in[1];
    const float* w_q  = (const float*)d_in[2];
    const float* w_k  = (const float*)d_in[3];
    const float* bias = (const float*)d_in[4];
    const float* a    = (const float*)d_in[5];
    float* out = (float*)d_out;

    float* pu = (float*)d_ws;                      // [B][NC][H]  = 1 MB
    float* pv = pu + (size_t)BB * NC * HH;         // [B][H][ND]  = 1 MB

    proj_cell_kernel<<<dim3(NC / 8, BB), 256, 0, stream>>>(cell, w_k, bias, pu);
    proj_drug_kernel<<<dim3(ND / 64, BB), 256, 0, stream>>>(drug, w_q, pv);
    coattn_kernel<<<dim3(ND / 256, NC / CHUNK, BB), 256, 0, stream>>>(pu, pv, a, out);
}